// Round 1
// baseline (102.277 us; speedup 1.0000x reference)
//
#include <hip/hip_runtime.h>
#include <math.h>

#define BEV_H 200
#define BEV_W 200
#define TILE_W 16
#define TILE_H 8
#define BLOCK 128
#define CHUNK 128
#define FSTRIDE 36   // 32 features + 4 pad to break 32-bank aliasing on staging writes
#define T_DEAD 1e-10f

// One block = one 16x8 pixel tile. Per chunk of 128 gaussians:
//   stage: each thread computes screen-space params for one gaussian, tests its
//          ellipse bbox against the tile, and an ORDER-PRESERVING block scan
//          compacts survivors into LDS (order matters: compositing is sequential in g).
//   render: every thread (one pixel each) walks the compacted list, updating
//           transmittance T and 32 fp32 accumulators.
__global__ __launch_bounds__(BLOCK) void render_kernel(
    const float* __restrict__ features, const float* __restrict__ means3D,
    const float* __restrict__ cov3D, const float* __restrict__ opac,
    float* __restrict__ out, int G)
{
    __shared__ float lds_p[CHUNK][8];
    __shared__ float lds_f[CHUNK * FSTRIDE];
    __shared__ int wave_tot[BLOCK / 64];

    const int tid = threadIdx.x;
    const int b  = blockIdx.z;
    const int j0 = blockIdx.x * TILE_W;
    const int i0 = blockIdx.y * TILE_H;
    const int j  = j0 + (tid & (TILE_W - 1));
    const int i  = i0 + (tid / TILE_W);
    const float fi = (float)i, fj = (float)j;
    const bool in_range = (i < BEV_H) && (j < BEV_W);

    float acc[32];
#pragma unroll
    for (int d = 0; d < 32; ++d) acc[d] = 0.0f;
    float T = in_range ? 1.0f : 0.0f;   // pad lanes start dead -> never enter hot branch

    const float ti_lo = (float)i0, ti_hi = (float)(i0 + TILE_H - 1);
    const float tj_lo = (float)j0, tj_hi = (float)(j0 + TILE_W - 1);

    for (int g0 = 0; g0 < G; g0 += CHUNK) {
        // Barrier doubles as (a) LDS reuse guard and (b) whole-block early exit.
        if (__syncthreads_and(T < T_DEAD)) break;

        // ---- stage one gaussian per thread ----
        const int g = g0 + tid;
        bool keep = false;
        float u = 0.f, v = 0.f, qa = 0.f, qb = 0.f, qc = 0.f, op = 0.f, pth = 0.f;
        if (g < G) {
            const float* m  = means3D + (size_t)(b * G + g) * 3;
            const float* cv = cov3D   + (size_t)(b * G + g) * 6;
            const float x = m[0], y = m[1];
            const float sxx = cv[0], sxy = cv[1], syy = cv[3];
            op = opac[b * G + g];
            u = -2.0f * y + 100.0f;          // sh = BEV_H/H_METERS = 2
            v = -2.0f * x + 100.0f;
            const float c00 = 4.0f * syy + 0.3f;
            const float c01 = 4.0f * sxy;
            const float c11 = 4.0f * sxx + 0.3f;
            const float det = c00 * c11 - c01 * c01;
            if (op > 0.05f && det > 0.0f) {
                const float inv = 1.0f / det;
                qa = -0.5f * (c11 * inv);    // -0.5*cA
                qb = c01 * inv;              // -cB  (cB = -c01*inv)
                qc = -0.5f * (c00 * inv);    // -0.5*cC
                const float L = logf(255.0f * op);   // > 0 since op > 0.05
                pth = -L;                    // keep iff power >= pth  (== alpha >= 1/255)
                // bbox half-widths of {x^T Cinv x <= 2L}: sqrt(2L * C_ii), + eps slack
                const float ru = sqrtf(2.0f * L * c00) + 0.01f;
                const float rv = sqrtf(2.0f * L * c11) + 0.01f;
                keep = (u + ru >= ti_lo) && (u - ru <= ti_hi) &&
                       (v + rv >= tj_lo) && (v - rv <= tj_hi);
            }
        }

        // ---- order-preserving compaction ----
        const unsigned long long bal = __ballot(keep);
        const int lane = tid & 63;
        const int wid  = tid >> 6;
        const int pre  = __popcll(bal & ((1ull << lane) - 1ull));
        if (lane == 0) wave_tot[wid] = __popcll(bal);
        __syncthreads();
        const int w0 = wave_tot[0];
        const int nk = w0 + wave_tot[1];
        const int slot = (wid ? w0 : 0) + pre;

        if (keep) {
            float* p = lds_p[slot];
            p[0] = u;  p[1] = v;  p[2] = qa; p[3] = qb;
            p[4] = qc; p[5] = op; p[6] = pth; p[7] = 0.0f;
            const float4* fsrc = (const float4*)(features + (size_t)(b * G + g) * 32);
            float4* fdst = (float4*)(lds_f + slot * FSTRIDE);
#pragma unroll
            for (int c = 0; c < 8; ++c) fdst[c] = fsrc[c];
        }
        __syncthreads();

        // ---- composite the compacted list (uniform k => LDS broadcast reads) ----
        for (int k = 0; k < nk; ++k) {
            const float4 p0 = *(const float4*)&lds_p[k][0];  // u v qa qb
            const float4 p1 = *(const float4*)&lds_p[k][4];  // qc op pth -
            const float du = p0.x - fi;
            const float dv = p0.y - fj;
            const float power = p0.z * du * du + p1.x * dv * dv + p0.w * du * dv;
            if (T >= T_DEAD && power <= 0.0f && power >= p1.z) {
                const float alpha = fminf(0.99f, p1.y * __expf(power));
                const float w = alpha * T;
                T *= 1.0f - alpha;
                const float* f = lds_f + k * FSTRIDE;
#pragma unroll
                for (int d = 0; d < 8; ++d) {
                    const float4 fv = *(const float4*)(f + 4 * d);
                    acc[4*d+0] = fmaf(w, fv.x, acc[4*d+0]);
                    acc[4*d+1] = fmaf(w, fv.y, acc[4*d+1]);
                    acc[4*d+2] = fmaf(w, fv.z, acc[4*d+2]);
                    acc[4*d+3] = fmaf(w, fv.w, acc[4*d+3]);
                }
            }
        }
    }

    if (in_range) {
        const size_t base = (size_t)b * 32 * (BEV_H * BEV_W) + (size_t)i * BEV_W + j;
#pragma unroll
        for (int d = 0; d < 32; ++d)
            out[base + (size_t)d * (BEV_H * BEV_W)] = acc[d];
    }
}

// num_gaussians = mean over batch of sum(op > 0.05) = total_count / B
__global__ void count_kernel(const float* __restrict__ opac, float* __restrict__ out,
                             int n, int out_idx, float inv_B)
{
    __shared__ float sdata[256];
    const int tid = threadIdx.x;
    float s = 0.0f;
    for (int idx = tid; idx < n; idx += 256)
        s += (opac[idx] > 0.05f) ? 1.0f : 0.0f;
    sdata[tid] = s;
    __syncthreads();
    for (int off = 128; off > 0; off >>= 1) {
        if (tid < off) sdata[tid] += sdata[tid + off];
        __syncthreads();
    }
    if (tid == 0) out[out_idx] = sdata[0] * inv_B;
}

extern "C" void kernel_launch(void* const* d_in, const int* in_sizes, int n_in,
                              void* d_out, int out_size, void* d_ws, size_t ws_size,
                              hipStream_t stream)
{
    const float* features = (const float*)d_in[0];
    const float* means3D  = (const float*)d_in[1];
    const float* cov3D    = (const float*)d_in[2];
    const float* opac     = (const float*)d_in[3];
    float* out = (float*)d_out;

    const int B = 2;
    const int G = in_sizes[3] / B;   // opacities is (B, G, 1)

    dim3 grid((BEV_W + TILE_W - 1) / TILE_W, (BEV_H + TILE_H - 1) / TILE_H, B);
    render_kernel<<<grid, BLOCK, 0, stream>>>(features, means3D, cov3D, opac, out, G);

    const int scalar_idx = B * 32 * BEV_H * BEV_W;   // == out_size - 1
    count_kernel<<<1, 256, 0, stream>>>(opac, out, B * G, scalar_idx, 1.0f / B);
}

// Round 2
// 101.274 us; speedup vs baseline: 1.0099x; 1.0099x over previous
//
#include <hip/hip_runtime.h>
#include <math.h>

#define BEV_H 200
#define BEV_W 200
#define NPIX (BEV_H * BEV_W)
#define TILE_W 16
#define TILE_H 8
#define BLOCK 128
#define CHUNK 128
#define FSTRIDE 36   // 32 features + 4 pad: spreads staging-write bank groups
#define T_DEAD 1e-10f
#define NSEG 4
#define NB 2

// Split-G compositing: out = acc_0 + T_0*(acc_1 + T_1*(acc_2 + T_2*acc_3))
// where (acc_s, T_s) is the alpha-compositing monoid over segment s of the
// gaussian list. Each block = (tile, batch, segment); 4x the blocks and 1/4
// the serial chain vs the round-1 kernel (which was latency-bound at 10% occ).
__global__ __launch_bounds__(BLOCK) void render_seg_kernel(
    const float* __restrict__ features, const float* __restrict__ means3D,
    const float* __restrict__ cov3D, const float* __restrict__ opac,
    float* __restrict__ ws_acc,   // [s][b][d][p]
    float* __restrict__ ws_T,     // [s][b][p]
    int G)
{
    __shared__ float lds_p[CHUNK][8];
    __shared__ float lds_f[CHUNK * FSTRIDE];
    __shared__ int wave_tot[BLOCK / 64];

    const int tid = threadIdx.x;
    const int b  = blockIdx.z & (NB - 1);
    const int s  = blockIdx.z / NB;
    const int j0 = blockIdx.x * TILE_W;
    const int i0 = blockIdx.y * TILE_H;
    const int j  = j0 + (tid & (TILE_W - 1));
    const int i  = i0 + (tid / TILE_W);
    const float fi = (float)i, fj = (float)j;
    const bool in_range = (i < BEV_H) && (j < BEV_W);

    const int g_lo = (s * G) / NSEG;
    const int g_hi = ((s + 1) * G) / NSEG;

    float acc[32];
#pragma unroll
    for (int d = 0; d < 32; ++d) acc[d] = 0.0f;
    float T = in_range ? 1.0f : 0.0f;   // pad lanes dead -> skip hot branch

    const float ti_lo = (float)i0, ti_hi = (float)(i0 + TILE_H - 1);
    const float tj_lo = (float)j0, tj_hi = (float)(j0 + TILE_W - 1);

    for (int g0 = g_lo; g0 < g_hi; g0 += CHUNK) {
        // Barrier doubles as LDS-reuse guard and whole-block early exit.
        if (__syncthreads_and(T < T_DEAD)) break;

        // ---- stage one gaussian per thread ----
        const int g = g0 + tid;
        bool keep = false;
        float u = 0.f, v = 0.f, qa = 0.f, qb = 0.f, qc = 0.f, op = 0.f, pth = 0.f;
        if (g < g_hi) {
            const float* m  = means3D + (size_t)(b * G + g) * 3;
            const float* cv = cov3D   + (size_t)(b * G + g) * 6;
            const float x = m[0], y = m[1];
            const float sxx = cv[0], sxy = cv[1], syy = cv[3];
            op = opac[b * G + g];
            u = -2.0f * y + 100.0f;          // sh = BEV_H/H_METERS = 2
            v = -2.0f * x + 100.0f;
            const float c00 = 4.0f * syy + 0.3f;
            const float c01 = 4.0f * sxy;
            const float c11 = 4.0f * sxx + 0.3f;
            const float det = c00 * c11 - c01 * c01;
            if (op > 0.05f && det > 0.0f) {
                const float inv = 1.0f / det;
                qa = -0.5f * (c11 * inv);
                qb = c01 * inv;              // == -cB
                qc = -0.5f * (c00 * inv);
                const float L = logf(255.0f * op);   // > 0 since op > 0.05
                pth = -L;                    // alpha >= 1/255  <=>  power >= pth
                const float ru = sqrtf(2.0f * L * c00) + 0.01f;
                const float rv = sqrtf(2.0f * L * c11) + 0.01f;
                keep = (u + ru >= ti_lo) && (u - ru <= ti_hi) &&
                       (v + rv >= tj_lo) && (v - rv <= tj_hi);
            }
        }

        // ---- order-preserving compaction (ballot prefix scan) ----
        const unsigned long long bal = __ballot(keep);
        const int lane = tid & 63;
        const int wid  = tid >> 6;
        const int pre  = __popcll(bal & ((1ull << lane) - 1ull));
        if (lane == 0) wave_tot[wid] = __popcll(bal);
        __syncthreads();
        const int w0 = wave_tot[0];
        const int nk = w0 + wave_tot[1];
        const int slot = (wid ? w0 : 0) + pre;

        if (keep) {
            float* p = lds_p[slot];
            p[0] = u;  p[1] = v;  p[2] = qa; p[3] = qb;
            p[4] = qc; p[5] = op; p[6] = pth; p[7] = 0.0f;
            const float4* fsrc = (const float4*)(features + (size_t)(b * G + g) * 32);
            float4* fdst = (float4*)(lds_f + slot * FSTRIDE);
#pragma unroll
            for (int c = 0; c < 8; ++c) fdst[c] = fsrc[c];
        }
        __syncthreads();

        // ---- composite compacted list (uniform k => LDS broadcast reads) ----
        for (int k = 0; k < nk; ++k) {
            const float4 p0 = *(const float4*)&lds_p[k][0];  // u v qa qb
            const float4 p1 = *(const float4*)&lds_p[k][4];  // qc op pth -
            const float du = p0.x - fi;
            const float dv = p0.y - fj;
            const float power = p0.z * du * du + p1.x * dv * dv + p0.w * du * dv;
            if (T >= T_DEAD && power <= 0.0f && power >= p1.z) {
                const float alpha = fminf(0.99f, p1.y * __expf(power));
                const float w = alpha * T;
                T *= 1.0f - alpha;
                const float* f = lds_f + k * FSTRIDE;
#pragma unroll
                for (int d = 0; d < 8; ++d) {
                    const float4 fv = *(const float4*)(f + 4 * d);
                    acc[4*d+0] = fmaf(w, fv.x, acc[4*d+0]);
                    acc[4*d+1] = fmaf(w, fv.y, acc[4*d+1]);
                    acc[4*d+2] = fmaf(w, fv.z, acc[4*d+2]);
                    acc[4*d+3] = fmaf(w, fv.w, acc[4*d+3]);
                }
            }
        }
    }

    if (in_range) {
        const int p = i * BEV_W + j;
        float* ab = ws_acc + ((size_t)(s * NB + b) * 32) * NPIX + p;
#pragma unroll
        for (int d = 0; d < 32; ++d) ab[(size_t)d * NPIX] = acc[d];
        ws_T[(size_t)(s * NB + b) * NPIX + p] = T;
    }
}

// Combine 4 segment partials + fold in the gaussian count (last block).
__global__ __launch_bounds__(256) void combine_kernel(
    const float* __restrict__ ws_acc, const float* __restrict__ ws_T,
    const float* __restrict__ opac, float* __restrict__ out, int G)
{
    if (blockIdx.x == gridDim.x - 1) {
        // num_gaussians = sum(op > 0.05) / B
        __shared__ float sdata[256];
        const int tid = threadIdx.x;
        float cs = 0.0f;
        const int n = NB * G;
        for (int idx = tid; idx < n; idx += 256)
            cs += (opac[idx] > 0.05f) ? 1.0f : 0.0f;
        sdata[tid] = cs;
        __syncthreads();
        for (int off = 128; off > 0; off >>= 1) {
            if (tid < off) sdata[tid] += sdata[tid + off];
            __syncthreads();
        }
        if (tid == 0) out[NB * 32 * NPIX] = sdata[0] * (1.0f / NB);
        return;
    }

    const int flat = blockIdx.x * 256 + threadIdx.x;   // (b, p)
    if (flat >= NB * NPIX) return;
    const int b = flat / NPIX;
    const int p = flat - b * NPIX;

    const float T0 = ws_T[(size_t)(0 * NB + b) * NPIX + p];
    const float T1 = ws_T[(size_t)(1 * NB + b) * NPIX + p];
    const float T2 = ws_T[(size_t)(2 * NB + b) * NPIX + p];

    const float* a0 = ws_acc + ((size_t)(0 * NB + b) * 32) * NPIX + p;
    const float* a1 = ws_acc + ((size_t)(1 * NB + b) * 32) * NPIX + p;
    const float* a2 = ws_acc + ((size_t)(2 * NB + b) * 32) * NPIX + p;
    const float* a3 = ws_acc + ((size_t)(3 * NB + b) * 32) * NPIX + p;
    float* ob = out + ((size_t)b * 32) * NPIX + p;

#pragma unroll
    for (int d = 0; d < 32; ++d) {
        const size_t o = (size_t)d * NPIX;
        ob[o] = a0[o] + T0 * (a1[o] + T1 * (a2[o] + T2 * a3[o]));
    }
}

extern "C" void kernel_launch(void* const* d_in, const int* in_sizes, int n_in,
                              void* d_out, int out_size, void* d_ws, size_t ws_size,
                              hipStream_t stream)
{
    const float* features = (const float*)d_in[0];
    const float* means3D  = (const float*)d_in[1];
    const float* cov3D    = (const float*)d_in[2];
    const float* opac     = (const float*)d_in[3];
    float* out = (float*)d_out;

    const int G = in_sizes[3] / NB;   // opacities is (B, G, 1)

    float* ws_acc = (float*)d_ws;                                  // S*B*32*NPIX
    float* ws_T   = ws_acc + (size_t)NSEG * NB * 32 * NPIX;        // S*B*NPIX

    dim3 grid((BEV_W + TILE_W - 1) / TILE_W, (BEV_H + TILE_H - 1) / TILE_H,
              NB * NSEG);
    render_seg_kernel<<<grid, BLOCK, 0, stream>>>(features, means3D, cov3D, opac,
                                                  ws_acc, ws_T, G);

    const int nblk = (NB * NPIX + 255) / 256 + 1;   // +1: count block
    combine_kernel<<<nblk, 256, 0, stream>>>(ws_acc, ws_T, opac, out, G);
}